// Round 1
// baseline (1345.622 us; speedup 1.0000x reference)
//
#include <hip/hip_runtime.h>
#include <math.h>

// ---------- degree / norm ----------
__global__ void k_deg_init(float* deg, int n) {
    int i = blockIdx.x * blockDim.x + threadIdx.x;
    if (i < n) deg[i] = 1.0f;  // self-loop contributes 1
}

__global__ void k_deg_edges(const int* dst, float* deg, int e) {
    int i = blockIdx.x * blockDim.x + threadIdx.x;
    if (i < e) atomicAdd(&deg[dst[i]], 1.0f);
}

__global__ void k_dinv(float* deg, int n) {
    int i = blockIdx.x * blockDim.x + threadIdx.x;
    if (i < n) deg[i] = rsqrtf(deg[i]);  // deg >= 1 always (self-loops)
}

// ---------- layer-1 aggregation on raw 2-feature input (A @ x) ----------
__global__ void k_aggx_init(const float* x, const float* dinv, float* out, int n) {
    int i = blockIdx.x * blockDim.x + threadIdx.x;
    if (i < n) {
        float d = dinv[i]; float d2 = d * d;
        out[2 * i]     = d2 * x[2 * i];
        out[2 * i + 1] = d2 * x[2 * i + 1];
    }
}

__global__ void k_aggx_edges(const int* src, const int* dst, const float* x,
                             const float* dinv, float* out, int e) {
    int i = blockIdx.x * blockDim.x + threadIdx.x;
    if (i < e) {
        int s = src[i], d = dst[i];
        float w = dinv[s] * dinv[d];
        atomicAdd(&out[2 * d],     w * x[2 * s]);
        atomicAdd(&out[2 * d + 1], w * x[2 * s + 1]);
    }
}

// h1 = relu(aggx @ W1 + b1), W1 is [2,64]
__global__ void k_lin1(const float* aggx, const float* W1, const float* b1,
                       float* h, int n) {
    int t = blockIdx.x * blockDim.x + threadIdx.x;
    if (t < n * 64) {
        int i = t >> 6, j = t & 63;
        float v = aggx[2 * i] * W1[j] + aggx[2 * i + 1] * W1[64 + j] + b1[j];
        h[t] = fmaxf(v, 0.0f);
    }
}

// ---------- width-64 aggregation: out = A_norm @ h ----------
__global__ void k_agg64_init(const float* h, const float* dinv, float* out, int n) {
    int t = blockIdx.x * blockDim.x + threadIdx.x;
    if (t < n * 64) {
        int i = t >> 6;
        float d = dinv[i];
        out[t] = d * d * h[t];
    }
}

__global__ void k_agg64_edges(const int* src, const int* dst, const float* h,
                              const float* dinv, float* out, int e) {
    int t = blockIdx.x * blockDim.x + threadIdx.x;
    if (t < e * 64) {
        int ei = t >> 6, j = t & 63;
        int s = src[ei], d = dst[ei];
        float w = dinv[s] * dinv[d];
        atomicAdd(&out[d * 64 + j], w * h[s * 64 + j]);
    }
}

// out = act(in @ W + b), W is [64,64] row-major; block covers 4 rows
__global__ void k_lin64(const float* __restrict__ in, const float* __restrict__ W,
                        const float* __restrict__ b, float* __restrict__ out,
                        int n, int do_relu) {
    __shared__ float Ws[64 * 64];
    __shared__ float xs[256];
    int tid = threadIdx.x;
    for (int k = tid; k < 64 * 64; k += 256) Ws[k] = W[k];
    int t = blockIdx.x * 256 + tid;
    xs[tid] = (t < n * 64) ? in[t] : 0.0f;
    __syncthreads();
    if (t < n * 64) {
        int j = tid & 63, r = tid >> 6;
        float acc = b[j];
        #pragma unroll
        for (int k = 0; k < 64; k++) acc += xs[r * 64 + k] * Ws[k * 64 + j];
        out[t] = do_relu ? fmaxf(acc, 0.0f) : acc;
    }
}

// ---------- mean pool ----------
__global__ void k_pool(const float* h, const int* batch, float* sums, float* cnt, int n) {
    int t = blockIdx.x * blockDim.x + threadIdx.x;
    if (t < n * 64) {
        int i = t >> 6, j = t & 63;
        int g = batch[i];
        atomicAdd(&sums[g * 64 + j], h[t]);
        if (j == 0) atomicAdd(&cnt[g], 1.0f);
    }
}

// ---------- head: concat(pooled, ge) @ Wl + bl, log_softmax ----------
__global__ void k_head(const float* sums, const float* cnt, const float* ge,
                       const float* Wl, const float* bl, float* out, int ng) {
    int g = blockIdx.x * blockDim.x + threadIdx.x;
    if (g < ng) {
        float c = fmaxf(cnt[g], 1.0f);
        float z[5];
        for (int cl = 0; cl < 5; cl++) z[cl] = bl[cl];
        for (int k = 0; k < 64; k++) {
            float p = sums[g * 64 + k] / c;
            for (int cl = 0; cl < 5; cl++) z[cl] += p * Wl[k * 5 + cl];
        }
        for (int k = 0; k < 64; k++) {
            float p = ge[g * 64 + k];
            for (int cl = 0; cl < 5; cl++) z[cl] += p * Wl[(64 + k) * 5 + cl];
        }
        float m = z[0];
        for (int cl = 1; cl < 5; cl++) m = fmaxf(m, z[cl]);
        float s = 0.0f;
        for (int cl = 0; cl < 5; cl++) s += expf(z[cl] - m);
        float lse = m + logf(s);
        for (int cl = 0; cl < 5; cl++) out[g * 5 + cl] = z[cl] - lse;
    }
}

extern "C" void kernel_launch(void* const* d_in, const int* in_sizes, int n_in,
                              void* d_out, int out_size, void* d_ws, size_t ws_size,
                              hipStream_t stream) {
    const float* x    = (const float*)d_in[0];
    const int*   ei   = (const int*)d_in[1];
    const int*   batch= (const int*)d_in[2];
    const float* ge   = (const float*)d_in[3];
    const float* W1   = (const float*)d_in[4];
    const float* b1   = (const float*)d_in[5];
    const float* W2   = (const float*)d_in[6];
    const float* b2   = (const float*)d_in[7];
    const float* W3   = (const float*)d_in[8];
    const float* b3   = (const float*)d_in[9];
    const float* Wl   = (const float*)d_in[10];
    const float* bl   = (const float*)d_in[11];
    float* out = (float*)d_out;

    const int N = in_sizes[0] / 2;   // x is [N,2]
    const int E = in_sizes[1] / 2;   // edge_index is [2,E]
    const int NG = 128;
    const int* src = ei;
    const int* dst = ei + E;

    float* ws   = (float*)d_ws;
    float* dinv = ws;                 // N   (deg, then rsqrt in place)
    float* aggx = ws + N;             // 2N
    float* bufA = ws + 3 * N;         // 64N
    float* bufB = bufA + 64 * N;      // 64N
    float* sums = bufB + 64 * N;      // NG*64
    float* cnt  = sums + NG * 64;     // NG

    const int BS = 256;
    int gN    = (N + BS - 1) / BS;
    int gE    = (E + BS - 1) / BS;
    int gN64  = (N * 64 + BS - 1) / BS;
    int gE64  = (E * 64 + BS - 1) / BS;

    // degrees + norm
    k_deg_init<<<gN, BS, 0, stream>>>(dinv, N);
    hipMemsetAsync(sums, 0, (NG * 64 + NG) * sizeof(float), stream);
    k_deg_edges<<<gE, BS, 0, stream>>>(dst, dinv, E);
    k_dinv<<<gN, BS, 0, stream>>>(dinv, N);

    // layer 1: aggregate raw 2-feature x, then linear+relu
    k_aggx_init<<<gN, BS, 0, stream>>>(x, dinv, aggx, N);
    k_aggx_edges<<<gE, BS, 0, stream>>>(src, dst, x, dinv, aggx, E);
    k_lin1<<<gN64, BS, 0, stream>>>(aggx, W1, b1, bufA, N);   // h1 in A

    // layer 2: t2 = A@h1 (B), h2 = relu(t2@W2+b2) (A)
    k_agg64_init<<<gN64, BS, 0, stream>>>(bufA, dinv, bufB, N);
    k_agg64_edges<<<gE64, BS, 0, stream>>>(src, dst, bufA, dinv, bufB, E);
    k_lin64<<<gN64, BS, 0, stream>>>(bufB, W2, b2, bufA, N, 1); // h2 in A

    // layer 3: t3 = A@h2 (B), h3 = t3@W3+b3 (A)
    k_agg64_init<<<gN64, BS, 0, stream>>>(bufA, dinv, bufB, N);
    k_agg64_edges<<<gE64, BS, 0, stream>>>(src, dst, bufA, dinv, bufB, E);
    k_lin64<<<gN64, BS, 0, stream>>>(bufB, W3, b3, bufA, N, 0); // h3 in A

    // pool + head
    k_pool<<<gN64, BS, 0, stream>>>(bufA, batch, sums, cnt, N);
    k_head<<<1, 128, 0, stream>>>(sums, cnt, ge, Wl, bl, out, NG);
}

// Round 2
// 851.007 us; speedup vs baseline: 1.5812x; 1.5812x over previous
//
#include <hip/hip_runtime.h>
#include <math.h>

// ---------- degree / norm ----------
__global__ void k_deg_init(float* deg, int n) {
    int i = blockIdx.x * blockDim.x + threadIdx.x;
    if (i < n) deg[i] = 1.0f;  // self-loop contributes 1
}

__global__ void k_deg_edges(const int* dst, float* deg, int e) {
    int i = blockIdx.x * blockDim.x + threadIdx.x;
    if (i < e) atomicAdd(&deg[dst[i]], 1.0f);
}

__global__ void k_dinv(float* deg, int n) {
    int i = blockIdx.x * blockDim.x + threadIdx.x;
    if (i < n) deg[i] = rsqrtf(deg[i]);  // deg >= 1 always (self-loops)
}

// ---------- layer-1 aggregation on raw 2-feature input (A @ x) ----------
__global__ void k_aggx_init(const float* x, const float* dinv, float* out, int n) {
    int i = blockIdx.x * blockDim.x + threadIdx.x;
    if (i < n) {
        float d = dinv[i]; float d2 = d * d;
        out[2 * i]     = d2 * x[2 * i];
        out[2 * i + 1] = d2 * x[2 * i + 1];
    }
}

__global__ void k_aggx_edges(const int* src, const int* dst, const float* x,
                             const float* dinv, float* out, int e) {
    int i = blockIdx.x * blockDim.x + threadIdx.x;
    if (i < e) {
        int s = src[i], d = dst[i];
        float w = dinv[s] * dinv[d];
        atomicAdd(&out[2 * d],     w * x[2 * s]);
        atomicAdd(&out[2 * d + 1], w * x[2 * s + 1]);
    }
}

// h = relu(aggx @ W1 + b1), W1 is [2,64]; also h2 = dinv^2 * h (self-loop init)
__global__ void k_lin1_dual(const float* aggx, const float* W1, const float* b1,
                            const float* dinv, float* h, float* h2, int n) {
    int t = blockIdx.x * blockDim.x + threadIdx.x;
    if (t < n * 64) {
        int i = t >> 6, j = t & 63;
        float v = aggx[2 * i] * W1[j] + aggx[2 * i + 1] * W1[64 + j] + b1[j];
        v = fmaxf(v, 0.0f);
        h[t] = v;
        float d = dinv[i];
        h2[t] = d * d * v;
    }
}

// ---------- width-64 edge scatter: out += w * h[src] ----------
__global__ void k_agg64_edges(const int* src, const int* dst, const float* h,
                              const float* dinv, float* out, int e) {
    int t = blockIdx.x * blockDim.x + threadIdx.x;
    if (t < e * 64) {
        int ei = t >> 6, j = t & 63;
        int s = src[ei], d = dst[ei];
        float w = dinv[s] * dinv[d];
        atomicAdd(&out[d * 64 + j], w * h[s * 64 + j]);
    }
}

// out = act(in @ W + b); optionally out2 = dinv^2 * out (self-loop init for
// the NEXT aggregation). Reads only the block's own 256-element input range
// into LDS before any write, so out/out2 may alias `in` safely.
__global__ void k_lin64(const float* __restrict__ in, const float* __restrict__ W,
                        const float* __restrict__ b, const float* __restrict__ dinv,
                        float* __restrict__ out, float* __restrict__ out2,
                        int n, int do_relu) {
    __shared__ float Ws[64 * 64];
    __shared__ float xs[256];
    int tid = threadIdx.x;
    for (int k = tid; k < 64 * 64; k += 256) Ws[k] = W[k];
    int t = blockIdx.x * 256 + tid;
    xs[tid] = (t < n * 64) ? in[t] : 0.0f;
    __syncthreads();
    if (t < n * 64) {
        int j = tid & 63, r = tid >> 6, i = t >> 6;
        float acc = b[j];
        #pragma unroll
        for (int k = 0; k < 64; k++) acc += xs[r * 64 + k] * Ws[k * 64 + j];
        if (do_relu) acc = fmaxf(acc, 0.0f);
        out[t] = acc;
        if (out2) {
            float d = dinv[i];
            out2[t] = d * d * acc;
        }
    }
}

// ---------- segmented mean-pool: batch is sorted, one block per graph ----------
__device__ inline int lower_bound_i(const int* __restrict__ a, int n, int key) {
    int lo = 0, hi = n;
    while (lo < hi) {
        int mid = (lo + hi) >> 1;
        if (a[mid] < key) lo = mid + 1; else hi = mid;
    }
    return lo;
}

__global__ void k_pool_seg(const float* __restrict__ h, const int* __restrict__ batch,
                           float* __restrict__ sums, float* __restrict__ cnt, int n) {
    int g = blockIdx.x;
    int lo = lower_bound_i(batch, n, g);
    int hi = lower_bound_i(batch, n, g + 1);
    __shared__ float part[256];
    int j = threadIdx.x & 63, r = threadIdx.x >> 6;
    float acc = 0.0f;
    for (int i = lo + r; i < hi; i += 4) acc += h[i * 64 + j];
    part[threadIdx.x] = acc;
    __syncthreads();
    if (threadIdx.x < 64) {
        float s = part[j] + part[64 + j] + part[128 + j] + part[192 + j];
        sums[g * 64 + j] = s;
        if (j == 0) cnt[g] = (float)(hi - lo);
    }
}

// ---------- head: concat(pooled, ge) @ Wl + bl, log_softmax ----------
__global__ void k_head(const float* sums, const float* cnt, const float* ge,
                       const float* Wl, const float* bl, float* out, int ng) {
    int g = blockIdx.x * blockDim.x + threadIdx.x;
    if (g < ng) {
        float c = fmaxf(cnt[g], 1.0f);
        float z[5];
        for (int cl = 0; cl < 5; cl++) z[cl] = bl[cl];
        for (int k = 0; k < 64; k++) {
            float p = sums[g * 64 + k] / c;
            for (int cl = 0; cl < 5; cl++) z[cl] += p * Wl[k * 5 + cl];
        }
        for (int k = 0; k < 64; k++) {
            float p = ge[g * 64 + k];
            for (int cl = 0; cl < 5; cl++) z[cl] += p * Wl[(64 + k) * 5 + cl];
        }
        float m = z[0];
        for (int cl = 1; cl < 5; cl++) m = fmaxf(m, z[cl]);
        float s = 0.0f;
        for (int cl = 0; cl < 5; cl++) s += expf(z[cl] - m);
        float lse = m + logf(s);
        for (int cl = 0; cl < 5; cl++) out[g * 5 + cl] = z[cl] - lse;
    }
}

extern "C" void kernel_launch(void* const* d_in, const int* in_sizes, int n_in,
                              void* d_out, int out_size, void* d_ws, size_t ws_size,
                              hipStream_t stream) {
    const float* x    = (const float*)d_in[0];
    const int*   ei   = (const int*)d_in[1];
    const int*   batch= (const int*)d_in[2];
    const float* ge   = (const float*)d_in[3];
    const float* W1   = (const float*)d_in[4];
    const float* b1   = (const float*)d_in[5];
    const float* W2   = (const float*)d_in[6];
    const float* b2   = (const float*)d_in[7];
    const float* W3   = (const float*)d_in[8];
    const float* b3   = (const float*)d_in[9];
    const float* Wl   = (const float*)d_in[10];
    const float* bl   = (const float*)d_in[11];
    float* out = (float*)d_out;

    const int N = in_sizes[0] / 2;   // x is [N,2]
    const int E = in_sizes[1] / 2;   // edge_index is [2,E]
    const int NG = 128;
    const int* src = ei;
    const int* dst = ei + E;

    float* ws   = (float*)d_ws;
    float* dinv = ws;                 // N   (deg, then rsqrt in place)
    float* aggx = ws + N;             // 2N
    float* bufA = ws + 3 * N;         // 64N
    float* bufB = bufA + 64 * N;      // 64N
    float* sums = bufB + 64 * N;      // NG*64
    float* cnt  = sums + NG * 64;     // NG

    const int BS = 256;
    int gN    = (N + BS - 1) / BS;
    int gE    = (E + BS - 1) / BS;
    int gN64  = (N * 64 + BS - 1) / BS;
    int gE64  = (E * 64 + BS - 1) / BS;

    // degrees + norm
    k_deg_init<<<gN, BS, 0, stream>>>(dinv, N);
    k_deg_edges<<<gE, BS, 0, stream>>>(dst, dinv, E);
    k_dinv<<<gN, BS, 0, stream>>>(dinv, N);

    // layer 1: aggregate raw 2-feature x, then linear+relu (dual write: h1, d^2*h1)
    k_aggx_init<<<gN, BS, 0, stream>>>(x, dinv, aggx, N);
    k_aggx_edges<<<gE, BS, 0, stream>>>(src, dst, x, dinv, aggx, E);
    k_lin1_dual<<<gN64, BS, 0, stream>>>(aggx, W1, b1, dinv, bufA, bufB, N);

    // layer 2: bufB += edge-scatter of h1; h2 = relu(bufB@W2+b2) -> bufA,
    //          and bufB = d^2*h2 (in-place over input, safe per-block)
    k_agg64_edges<<<gE64, BS, 0, stream>>>(src, dst, bufA, dinv, bufB, E);
    k_lin64<<<gN64, BS, 0, stream>>>(bufB, W2, b2, dinv, bufA, bufB, N, 1);

    // layer 3: bufB += edge-scatter of h2; h3 = bufB@W3+b3 -> bufA
    k_agg64_edges<<<gE64, BS, 0, stream>>>(src, dst, bufA, dinv, bufB, E);
    k_lin64<<<gN64, BS, 0, stream>>>(bufB, W3, b3, dinv, bufA, nullptr, N, 0);

    // segmented mean-pool (batch sorted) + head
    k_pool_seg<<<NG, BS, 0, stream>>>(bufA, batch, sums, cnt, N);
    k_head<<<1, 128, 0, stream>>>(sums, cnt, ge, Wl, bl, out, NG);
}

// Round 3
// 522.578 us; speedup vs baseline: 2.5750x; 1.6285x over previous
//
#include <hip/hip_runtime.h>
#include <math.h>

#define NG 128

// ---------- CSR build ----------
__global__ void k_hist(const int* __restrict__ dst, int* __restrict__ counts, int e) {
    int i = blockIdx.x * blockDim.x + threadIdx.x;
    if (i < e) atomicAdd(&counts[dst[i]], 1);
}

// per-block exclusive scan of counts -> row_ptr(local); block totals -> blk_sums
__global__ void k_scan1(const int* __restrict__ counts, int* __restrict__ row_ptr,
                        int* __restrict__ blk_sums, int n) {
    __shared__ int s[256];
    int tid = threadIdx.x;
    int i = blockIdx.x * 256 + tid;
    int v = (i < n) ? counts[i] : 0;
    s[tid] = v;
    __syncthreads();
    for (int d = 1; d < 256; d <<= 1) {
        int t = (tid >= d) ? s[tid - d] : 0;
        __syncthreads();
        s[tid] += t;
        __syncthreads();
    }
    if (i < n) row_ptr[i] = s[tid] - v;  // exclusive
    if (tid == 255) blk_sums[blockIdx.x] = s[255];
}

// exclusive scan of blk_sums (<=512) in one block of 512
__global__ void k_scan2(int* __restrict__ blk_sums, int nb) {
    __shared__ int s[512];
    int tid = threadIdx.x;
    int v = (tid < nb) ? blk_sums[tid] : 0;
    s[tid] = v;
    __syncthreads();
    for (int d = 1; d < 512; d <<= 1) {
        int t = (tid >= d) ? s[tid - d] : 0;
        __syncthreads();
        s[tid] += t;
        __syncthreads();
    }
    if (tid < nb) blk_sums[tid] = s[tid] - v;  // exclusive
}

// finalize: row_ptr += block offset; cursor = row_ptr; dinv = rsqrt(count+1)
__global__ void k_scan3(int* __restrict__ row_ptr, const int* __restrict__ blk_sums,
                        const int* __restrict__ counts, int* __restrict__ cursor,
                        float* __restrict__ dinv, int n, int e_total) {
    int i = blockIdx.x * 256 + threadIdx.x;
    if (i < n) {
        int v = row_ptr[i] + blk_sums[blockIdx.x];
        row_ptr[i] = v;
        cursor[i] = v;
        dinv[i] = rsqrtf((float)counts[i] + 1.0f);  // +1 self-loop
        if (i == n - 1) row_ptr[n] = e_total;
    }
}

__global__ void k_scatter(const int* __restrict__ src, const int* __restrict__ dst,
                          const float* __restrict__ dinv, int* __restrict__ cursor,
                          int* __restrict__ csr_src, float* __restrict__ csr_w, int e) {
    int i = blockIdx.x * blockDim.x + threadIdx.x;
    if (i < e) {
        int s = src[i], d = dst[i];
        int pos = atomicAdd(&cursor[d], 1);
        csr_src[pos] = s;
        csr_w[pos] = dinv[s] * dinv[d];
    }
}

// ---------- layer-1 pull on raw 2-feature x (thread per node) ----------
__global__ void k_pull2(const int* __restrict__ row_ptr, const int* __restrict__ csr_src,
                        const float* __restrict__ csr_w, const float* __restrict__ x,
                        const float* __restrict__ dinv, float* __restrict__ out, int n) {
    int i = blockIdx.x * blockDim.x + threadIdx.x;
    if (i < n) {
        float dd = dinv[i], d2 = dd * dd;
        float a0 = d2 * x[2 * i], a1 = d2 * x[2 * i + 1];
        int lo = row_ptr[i], hi = row_ptr[i + 1];
        for (int k = lo; k < hi; k++) {
            int s = csr_src[k];
            float w = csr_w[k];
            a0 += w * x[2 * s];
            a1 += w * x[2 * s + 1];
        }
        out[2 * i] = a0;
        out[2 * i + 1] = a1;
    }
}

// h1 = relu(aggx @ W1 + b1), W1 is [2,64]
__global__ void k_lin1(const float* __restrict__ aggx, const float* __restrict__ W1,
                       const float* __restrict__ b1, float* __restrict__ h, int n) {
    int t = blockIdx.x * blockDim.x + threadIdx.x;
    if (t < n * 64) {
        int i = t >> 6, j = t & 63;
        float v = aggx[2 * i] * W1[j] + aggx[2 * i + 1] * W1[64 + j] + b1[j];
        h[t] = fmaxf(v, 0.0f);
    }
}

// ---------- width-64 pull aggregation: wave per node, lane = feature ----------
__global__ void k_pull64(const int* __restrict__ row_ptr, const int* __restrict__ csr_src,
                         const float* __restrict__ csr_w, const float* __restrict__ h,
                         const float* __restrict__ dinv, float* __restrict__ out, int n) {
    int node = blockIdx.x * (blockDim.x >> 6) + (threadIdx.x >> 6);
    int lane = threadIdx.x & 63;
    if (node >= n) return;
    float dd = dinv[node];
    float acc = dd * dd * h[node * 64 + lane];
    int lo = row_ptr[node], hi = row_ptr[node + 1];
    for (int base = lo; base < hi; base += 64) {
        int cnt = hi - base; if (cnt > 64) cnt = 64;
        int sidx = (base + lane < hi) ? csr_src[base + lane] : 0;   // parallel load
        float wv = (base + lane < hi) ? csr_w[base + lane] : 0.0f;
        for (int k = 0; k < cnt; k++) {
            int s = __shfl(sidx, k);
            float w = __shfl(wv, k);
            acc += w * h[s * 64 + lane];
        }
    }
    out[node * 64 + lane] = acc;
}

// out = act(in @ W + b), W is [64,64] row-major; block covers 4 rows
__global__ void k_lin64(const float* __restrict__ in, const float* __restrict__ W,
                        const float* __restrict__ b, float* __restrict__ out,
                        int n, int do_relu) {
    __shared__ float Ws[64 * 64];
    __shared__ float xs[256];
    int tid = threadIdx.x;
    for (int k = tid; k < 64 * 64; k += 256) Ws[k] = W[k];
    int t = blockIdx.x * 256 + tid;
    xs[tid] = (t < n * 64) ? in[t] : 0.0f;
    __syncthreads();
    if (t < n * 64) {
        int j = tid & 63, r = tid >> 6;
        float acc = b[j];
        #pragma unroll
        for (int k = 0; k < 64; k++) acc += xs[r * 64 + k] * Ws[k * 64 + j];
        out[t] = do_relu ? fmaxf(acc, 0.0f) : acc;
    }
}

// ---------- segmented mean-pool: batch is sorted, one block per graph ----------
__device__ inline int lower_bound_i(const int* __restrict__ a, int n, int key) {
    int lo = 0, hi = n;
    while (lo < hi) {
        int mid = (lo + hi) >> 1;
        if (a[mid] < key) lo = mid + 1; else hi = mid;
    }
    return lo;
}

__global__ void k_pool_seg(const float* __restrict__ h, const int* __restrict__ batch,
                           float* __restrict__ sums, float* __restrict__ cnt, int n) {
    int g = blockIdx.x;
    int lo = lower_bound_i(batch, n, g);
    int hi = lower_bound_i(batch, n, g + 1);
    __shared__ float part[256];
    int j = threadIdx.x & 63, r = threadIdx.x >> 6;
    float acc = 0.0f;
    for (int i = lo + r; i < hi; i += 4) acc += h[i * 64 + j];
    part[threadIdx.x] = acc;
    __syncthreads();
    if (threadIdx.x < 64) {
        float s = part[j] + part[64 + j] + part[128 + j] + part[192 + j];
        sums[g * 64 + j] = s;
        if (j == 0) cnt[g] = (float)(hi - lo);
    }
}

// ---------- head ----------
__global__ void k_head(const float* __restrict__ sums, const float* __restrict__ cnt,
                       const float* __restrict__ ge, const float* __restrict__ Wl,
                       const float* __restrict__ bl, float* __restrict__ out, int ng) {
    int g = blockIdx.x * blockDim.x + threadIdx.x;
    if (g < ng) {
        float c = fmaxf(cnt[g], 1.0f);
        float z[5];
        for (int cl = 0; cl < 5; cl++) z[cl] = bl[cl];
        for (int k = 0; k < 64; k++) {
            float p = sums[g * 64 + k] / c;
            for (int cl = 0; cl < 5; cl++) z[cl] += p * Wl[k * 5 + cl];
        }
        for (int k = 0; k < 64; k++) {
            float p = ge[g * 64 + k];
            for (int cl = 0; cl < 5; cl++) z[cl] += p * Wl[(64 + k) * 5 + cl];
        }
        float m = z[0];
        for (int cl = 1; cl < 5; cl++) m = fmaxf(m, z[cl]);
        float s = 0.0f;
        for (int cl = 0; cl < 5; cl++) s += expf(z[cl] - m);
        float lse = m + logf(s);
        for (int cl = 0; cl < 5; cl++) out[g * 5 + cl] = z[cl] - lse;
    }
}

extern "C" void kernel_launch(void* const* d_in, const int* in_sizes, int n_in,
                              void* d_out, int out_size, void* d_ws, size_t ws_size,
                              hipStream_t stream) {
    const float* x    = (const float*)d_in[0];
    const int*   ei   = (const int*)d_in[1];
    const int*   batch= (const int*)d_in[2];
    const float* ge   = (const float*)d_in[3];
    const float* W1   = (const float*)d_in[4];
    const float* b1   = (const float*)d_in[5];
    const float* W2   = (const float*)d_in[6];
    const float* b2   = (const float*)d_in[7];
    const float* W3   = (const float*)d_in[8];
    const float* b3   = (const float*)d_in[9];
    const float* Wl   = (const float*)d_in[10];
    const float* bl   = (const float*)d_in[11];
    float* out = (float*)d_out;

    const int N = in_sizes[0] / 2;   // x is [N,2]
    const int E = in_sizes[1] / 2;   // edge_index is [2,E]
    const int* src = ei;
    const int* dst = ei + E;

    // ---- workspace layout ----
    char* wsb = (char*)d_ws;
    float* dinv  = (float*)wsb;                 wsb += (size_t)N * 4;
    float* aggx  = (float*)wsb;                 wsb += (size_t)2 * N * 4;
    float* bufA  = (float*)wsb;                 wsb += (size_t)64 * N * 4;
    float* bufB  = (float*)wsb;                 wsb += (size_t)64 * N * 4;
    float* sums  = (float*)wsb;                 wsb += (size_t)NG * 64 * 4;
    float* cnt   = (float*)wsb;                 wsb += (size_t)NG * 4;
    float* csr_w = (float*)wsb;                 wsb += (size_t)E * 4;
    int*   counts= (int*)wsb;                   wsb += (size_t)N * 4;
    int*   row_ptr=(int*)wsb;                   wsb += (size_t)(N + 1) * 4;
    int*   cursor =(int*)wsb;                   wsb += (size_t)N * 4;
    int*   csr_src=(int*)wsb;                   wsb += (size_t)E * 4;
    int*   blk_sums=(int*)wsb;                  wsb += 512 * 4;

    const int BS = 256;
    int gN    = (N + BS - 1) / BS;        // 391
    int gE    = (E + BS - 1) / BS;
    int gN64  = (N * 64 + BS - 1) / BS;
    int gW    = (N + 3) / 4;              // pull64: 4 waves (nodes) per block

    // ---- CSR build ----
    hipMemsetAsync(counts, 0, (size_t)N * 4, stream);
    k_hist<<<gE, BS, 0, stream>>>(dst, counts, E);
    k_scan1<<<gN, BS, 0, stream>>>(counts, row_ptr, blk_sums, N);
    k_scan2<<<1, 512, 0, stream>>>(blk_sums, gN);
    k_scan3<<<gN, BS, 0, stream>>>(row_ptr, blk_sums, counts, cursor, dinv, N, E);
    k_scatter<<<gE, BS, 0, stream>>>(src, dst, dinv, cursor, csr_src, csr_w, E);

    // ---- layer 1 ----
    k_pull2<<<gN, BS, 0, stream>>>(row_ptr, csr_src, csr_w, x, dinv, aggx, N);
    k_lin1<<<gN64, BS, 0, stream>>>(aggx, W1, b1, bufA, N);

    // ---- layer 2 ----
    k_pull64<<<gW, BS, 0, stream>>>(row_ptr, csr_src, csr_w, bufA, dinv, bufB, N);
    k_lin64<<<gN64, BS, 0, stream>>>(bufB, W2, b2, bufA, N, 1);

    // ---- layer 3 ----
    k_pull64<<<gW, BS, 0, stream>>>(row_ptr, csr_src, csr_w, bufA, dinv, bufB, N);
    k_lin64<<<gN64, BS, 0, stream>>>(bufB, W3, b3, bufA, N, 0);

    // ---- pool + head ----
    k_pool_seg<<<NG, BS, 0, stream>>>(bufA, batch, sums, cnt, N);
    k_head<<<1, 128, 0, stream>>>(sums, cnt, ge, Wl, bl, out, NG);
}

// Round 4
// 375.575 us; speedup vs baseline: 3.5828x; 1.3914x over previous
//
#include <hip/hip_runtime.h>
#include <hip/hip_bf16.h>
#include <math.h>

#define NG 128

typedef __attribute__((ext_vector_type(8))) short short8;
typedef __attribute__((ext_vector_type(4))) float float4v;

static __device__ __forceinline__ float bf2f(__hip_bfloat16 v) { return __bfloat162float(v); }

// ---------- CSR build ----------
__global__ void k_hist(const int* __restrict__ dst, int* __restrict__ counts, int e) {
    int i = blockIdx.x * blockDim.x + threadIdx.x;
    if (i < e) atomicAdd(&counts[dst[i]], 1);
}

__global__ void k_scan1(const int* __restrict__ counts, int* __restrict__ row_ptr,
                        int* __restrict__ blk_sums, int n) {
    __shared__ int s[256];
    int tid = threadIdx.x;
    int i = blockIdx.x * 256 + tid;
    int v = (i < n) ? counts[i] : 0;
    s[tid] = v;
    __syncthreads();
    for (int d = 1; d < 256; d <<= 1) {
        int t = (tid >= d) ? s[tid - d] : 0;
        __syncthreads();
        s[tid] += t;
        __syncthreads();
    }
    if (i < n) row_ptr[i] = s[tid] - v;  // exclusive
    if (tid == 255) blk_sums[blockIdx.x] = s[255];
}

__global__ void k_scan2(int* __restrict__ blk_sums, int nb) {
    __shared__ int s[512];
    int tid = threadIdx.x;
    int v = (tid < nb) ? blk_sums[tid] : 0;
    s[tid] = v;
    __syncthreads();
    for (int d = 1; d < 512; d <<= 1) {
        int t = (tid >= d) ? s[tid - d] : 0;
        __syncthreads();
        s[tid] += t;
        __syncthreads();
    }
    if (tid < nb) blk_sums[tid] = s[tid] - v;  // exclusive
}

__global__ void k_scan3(int* __restrict__ row_ptr, const int* __restrict__ blk_sums,
                        const int* __restrict__ counts, int* __restrict__ cursor,
                        float* __restrict__ dinv, int n, int e_total) {
    int i = blockIdx.x * 256 + threadIdx.x;
    if (i < n) {
        int v = row_ptr[i] + blk_sums[blockIdx.x];
        row_ptr[i] = v;
        cursor[i] = v;
        dinv[i] = rsqrtf((float)counts[i] + 1.0f);  // +1 self-loop
        if (i == n - 1) row_ptr[n] = e_total;
    }
}

// packed edge: .x = src index, .y = float weight bits
__global__ void k_scatter(const int* __restrict__ src, const int* __restrict__ dst,
                          const float* __restrict__ dinv, int* __restrict__ cursor,
                          int2* __restrict__ edges, int e) {
    int i = blockIdx.x * blockDim.x + threadIdx.x;
    if (i < e) {
        int s = src[i], d = dst[i];
        int pos = atomicAdd(&cursor[d], 1);
        edges[pos] = make_int2(s, __float_as_int(dinv[s] * dinv[d]));
    }
}

// ---------- layer-1 pull on raw 2-feature x (thread per node) ----------
__global__ void k_pull2(const int* __restrict__ row_ptr, const int2* __restrict__ edges,
                        const float* __restrict__ x, const float* __restrict__ dinv,
                        float* __restrict__ out, int n) {
    int i = blockIdx.x * blockDim.x + threadIdx.x;
    if (i < n) {
        float dd = dinv[i], d2 = dd * dd;
        float a0 = d2 * x[2 * i], a1 = d2 * x[2 * i + 1];
        int lo = row_ptr[i], hi = row_ptr[i + 1];
        for (int k = lo; k < hi; k++) {
            int2 e = edges[k];
            float w = __int_as_float(e.y);
            a0 += w * x[2 * e.x];
            a1 += w * x[2 * e.x + 1];
        }
        out[2 * i] = a0;
        out[2 * i + 1] = a1;
    }
}

// h1 = relu(aggx @ W1 + b1) -> bf16
__global__ void k_lin1(const float* __restrict__ aggx, const float* __restrict__ W1,
                       const float* __restrict__ b1, __hip_bfloat16* __restrict__ h, int n) {
    int t = blockIdx.x * blockDim.x + threadIdx.x;
    if (t < n * 64) {
        int i = t >> 6, j = t & 63;
        float v = aggx[2 * i] * W1[j] + aggx[2 * i + 1] * W1[64 + j] + b1[j];
        h[t] = __float2bfloat16(fmaxf(v, 0.0f));
    }
}

// ---------- width-64 pull aggregation (bf16 gather, fp32 acc, bf16 out) ----------
__global__ void k_agg(const int* __restrict__ row_ptr, const int2* __restrict__ edges,
                      const __hip_bfloat16* __restrict__ h, const float* __restrict__ dinv,
                      __hip_bfloat16* __restrict__ out, int n) {
    int node = blockIdx.x * (blockDim.x >> 6) + (threadIdx.x >> 6);
    int lane = threadIdx.x & 63;
    if (node >= n) return;
    float dd = dinv[node];
    float acc = dd * dd * bf2f(h[(size_t)node * 64 + lane]);
    int lo = row_ptr[node], hi = row_ptr[node + 1];
    for (int base = lo; base < hi; base += 64) {
        int take = hi - base; if (take > 64) take = 64;
        int take4 = (take + 3) & ~3;     // pad to 4; pad lanes carry w=0, s=0
        int sl = 0; float wl = 0.0f;
        if (base + lane < hi) {
            int2 e = edges[base + lane];
            sl = e.x; wl = __int_as_float(e.y);
        }
        for (int k = 0; k < take4; k += 4) {
            int   s0 = __shfl(sl, k),     s1 = __shfl(sl, k + 1);
            int   s2 = __shfl(sl, k + 2), s3 = __shfl(sl, k + 3);
            float w0 = __shfl(wl, k),     w1 = __shfl(wl, k + 1);
            float w2 = __shfl(wl, k + 2), w3 = __shfl(wl, k + 3);
            float v0 = bf2f(h[(size_t)s0 * 64 + lane]);
            float v1 = bf2f(h[(size_t)s1 * 64 + lane]);
            float v2 = bf2f(h[(size_t)s2 * 64 + lane]);
            float v3 = bf2f(h[(size_t)s3 * 64 + lane]);
            acc += w0 * v0; acc += w1 * v1; acc += w2 * v2; acc += w3 * v3;
        }
    }
    out[(size_t)node * 64 + lane] = __float2bfloat16(acc);
}

// ---------- pack W (64x64 fp32) into MFMA B-fragment order, bf16 ----------
// chunk c = jt*2+half (jt: 16-col tile, half: K-half); lane l: n=l&15, q=l>>4
// Wf[(c*64+l)*8 + j] = W[(half*32 + q*8 + j)*64 + jt*16 + n]
__global__ void k_prepW(const float* __restrict__ W2, const float* __restrict__ W3,
                        __hip_bfloat16* __restrict__ Wf2, __hip_bfloat16* __restrict__ Wf3) {
    const float* W = blockIdx.x ? W3 : W2;
    __hip_bfloat16* Wf = blockIdx.x ? Wf3 : Wf2;
    int t = threadIdx.x;           // 0..511
    int c = t >> 6, l = t & 63;
    int jt = c >> 1, half = c & 1, nn = l & 15, q = l >> 4;
    #pragma unroll
    for (int j = 0; j < 8; j++) {
        int k = half * 32 + q * 8 + j;
        Wf[t * 8 + j] = __float2bfloat16(W[k * 64 + jt * 16 + nn]);
    }
}

// ---------- MFMA linear: out = act(in @ W + b); wave = 16 nodes ----------
template <int RELU, int OUTBF16>
__global__ void k_linM(const __hip_bfloat16* __restrict__ in,
                       const __hip_bfloat16* __restrict__ Wf,
                       const float* __restrict__ b,
                       __hip_bfloat16* __restrict__ out16,
                       float* __restrict__ out32, int n) {
    int wave = threadIdx.x >> 6, lane = threadIdx.x & 63;
    int nb = (blockIdx.x * (blockDim.x >> 6) + wave) * 16;
    if (nb >= n) return;
    int m = lane & 15, q = lane >> 4;
    int arow = nb + m; if (arow >= n) arow = n - 1;
    // A fragments: A[m][k], k = half*32 + q*8 + j  (16B contiguous loads)
    short8 a0 = *reinterpret_cast<const short8*>(in + (size_t)arow * 64 + q * 8);
    short8 a1 = *reinterpret_cast<const short8*>(in + (size_t)arow * 64 + 32 + q * 8);
    #pragma unroll
    for (int jt = 0; jt < 4; jt++) {
        short8 bf0 = *reinterpret_cast<const short8*>(Wf + ((size_t)(jt * 2 + 0) * 64 + lane) * 8);
        short8 bf1 = *reinterpret_cast<const short8*>(Wf + ((size_t)(jt * 2 + 1) * 64 + lane) * 8);
        float4v d = {0.0f, 0.0f, 0.0f, 0.0f};
        d = __builtin_amdgcn_mfma_f32_16x16x32_bf16(a0, bf0, d, 0, 0, 0);
        d = __builtin_amdgcn_mfma_f32_16x16x32_bf16(a1, bf1, d, 0, 0, 0);
        float bias = b[jt * 16 + m];           // C/D col = lane&15
        #pragma unroll
        for (int r = 0; r < 4; r++) {
            int row = q * 4 + r;               // C/D row = quad*4 + reg
            int node = nb + row;
            if (node < n) {
                float v = d[r] + bias;
                if (RELU) v = fmaxf(v, 0.0f);
                size_t off = (size_t)node * 64 + jt * 16 + m;
                if (OUTBF16) out16[off] = __float2bfloat16(v);
                else         out32[off] = v;
            }
        }
    }
}

// ---------- segmented mean-pool: batch sorted, one block per graph ----------
__device__ inline int lower_bound_i(const int* __restrict__ a, int n, int key) {
    int lo = 0, hi = n;
    while (lo < hi) {
        int mid = (lo + hi) >> 1;
        if (a[mid] < key) lo = mid + 1; else hi = mid;
    }
    return lo;
}

__global__ void k_pool_seg(const float* __restrict__ h, const int* __restrict__ batch,
                           float* __restrict__ sums, float* __restrict__ cnt, int n) {
    int g = blockIdx.x;
    int lo = lower_bound_i(batch, n, g);
    int hi = lower_bound_i(batch, n, g + 1);
    __shared__ float part[256];
    int j = threadIdx.x & 63, r = threadIdx.x >> 6;
    float acc = 0.0f;
    for (int i = lo + r; i < hi; i += 4) acc += h[(size_t)i * 64 + j];
    part[threadIdx.x] = acc;
    __syncthreads();
    if (threadIdx.x < 64) {
        float s = part[j] + part[64 + j] + part[128 + j] + part[192 + j];
        sums[g * 64 + j] = s;
        if (j == 0) cnt[g] = (float)(hi - lo);
    }
}

// ---------- head ----------
__global__ void k_head(const float* __restrict__ sums, const float* __restrict__ cnt,
                       const float* __restrict__ ge, const float* __restrict__ Wl,
                       const float* __restrict__ bl, float* __restrict__ out, int ng) {
    int g = blockIdx.x * blockDim.x + threadIdx.x;
    if (g < ng) {
        float c = fmaxf(cnt[g], 1.0f);
        float z[5];
        for (int cl = 0; cl < 5; cl++) z[cl] = bl[cl];
        for (int k = 0; k < 64; k++) {
            float p = sums[g * 64 + k] / c;
            for (int cl = 0; cl < 5; cl++) z[cl] += p * Wl[k * 5 + cl];
        }
        for (int k = 0; k < 64; k++) {
            float p = ge[g * 64 + k];
            for (int cl = 0; cl < 5; cl++) z[cl] += p * Wl[(64 + k) * 5 + cl];
        }
        float m = z[0];
        for (int cl = 1; cl < 5; cl++) m = fmaxf(m, z[cl]);
        float s = 0.0f;
        for (int cl = 0; cl < 5; cl++) s += expf(z[cl] - m);
        float lse = m + logf(s);
        for (int cl = 0; cl < 5; cl++) out[g * 5 + cl] = z[cl] - lse;
    }
}

extern "C" void kernel_launch(void* const* d_in, const int* in_sizes, int n_in,
                              void* d_out, int out_size, void* d_ws, size_t ws_size,
                              hipStream_t stream) {
    const float* x    = (const float*)d_in[0];
    const int*   ei   = (const int*)d_in[1];
    const int*   batch= (const int*)d_in[2];
    const float* ge   = (const float*)d_in[3];
    const float* W1   = (const float*)d_in[4];
    const float* b1   = (const float*)d_in[5];
    const float* W2   = (const float*)d_in[6];
    const float* b2   = (const float*)d_in[7];
    const float* W3   = (const float*)d_in[8];
    const float* b3   = (const float*)d_in[9];
    const float* Wl   = (const float*)d_in[10];
    const float* bl   = (const float*)d_in[11];
    float* out = (float*)d_out;

    const int N = in_sizes[0] / 2;   // x is [N,2]
    const int E = in_sizes[1] / 2;   // edge_index is [2,E]
    const int* src = ei;
    const int* dst = ei + E;

    // ---- workspace layout (all segments 16B-aligned) ----
    char* wsb = (char*)d_ws;
    float* dinv   = (float*)wsb;                wsb += (size_t)N * 4;            // 400 KB
    float* aggx   = (float*)wsb;                wsb += (size_t)2 * N * 4;        // 800 KB
    __hip_bfloat16* h16  = (__hip_bfloat16*)wsb; wsb += (size_t)64 * N * 2;      // 12.8 MB (h1, then h2)
    __hip_bfloat16* agg16= (__hip_bfloat16*)wsb; wsb += (size_t)64 * N * 2;      // 12.8 MB
    float* h3     = (float*)wsb;                wsb += (size_t)64 * N * 4;       // 25.6 MB
    float* sums   = (float*)wsb;                wsb += (size_t)NG * 64 * 4;
    float* cnt    = (float*)wsb;                wsb += (size_t)NG * 4;
    __hip_bfloat16* Wf2 = (__hip_bfloat16*)wsb; wsb += 4096 * 2;
    __hip_bfloat16* Wf3 = (__hip_bfloat16*)wsb; wsb += 4096 * 2;
    int2*  edges  = (int2*)wsb;                 wsb += (size_t)E * 8;            // 8 MB
    int*   counts = (int*)wsb;                  wsb += (size_t)N * 4;
    int*   cursor = (int*)wsb;                  wsb += (size_t)N * 4;
    int*   row_ptr= (int*)wsb;                  wsb += (size_t)(N + 1) * 4;
    int*   blk_sums=(int*)wsb;                  wsb += 512 * 4;

    const int BS = 256;
    int gN   = (N + BS - 1) / BS;
    int gE   = (E + BS - 1) / BS;
    int gN64 = (N * 64 + BS - 1) / BS;
    int gW   = (N + 3) / 4;                      // k_agg: 4 waves per block
    int gM   = ((N + 15) / 16 + 3) / 4;          // k_linM: 4 waves * 16 nodes per block

    // ---- CSR build ----
    hipMemsetAsync(counts, 0, (size_t)N * 4, stream);
    k_hist<<<gE, BS, 0, stream>>>(dst, counts, E);
    k_scan1<<<gN, BS, 0, stream>>>(counts, row_ptr, blk_sums, N);
    k_scan2<<<1, 512, 0, stream>>>(blk_sums, gN);
    k_scan3<<<gN, BS, 0, stream>>>(row_ptr, blk_sums, counts, cursor, dinv, N, E);
    k_scatter<<<gE, BS, 0, stream>>>(src, dst, dinv, cursor, edges, E);
    k_prepW<<<2, 512, 0, stream>>>(W2, W3, Wf2, Wf3);

    // ---- layer 1 ----
    k_pull2<<<gN, BS, 0, stream>>>(row_ptr, edges, x, dinv, aggx, N);
    k_lin1<<<gN64, BS, 0, stream>>>(aggx, W1, b1, h16, N);

    // ---- layer 2: agg = A@h1 ; h2 = relu(agg@W2+b2) (overwrites h1) ----
    k_agg<<<gW, BS, 0, stream>>>(row_ptr, edges, h16, dinv, agg16, N);
    k_linM<1, 1><<<gM, BS, 0, stream>>>(agg16, Wf2, b2, h16, nullptr, N);

    // ---- layer 3: agg = A@h2 ; h3 = agg@W3+b3 (fp32 for pool) ----
    k_agg<<<gW, BS, 0, stream>>>(row_ptr, edges, h16, dinv, agg16, N);
    k_linM<0, 0><<<gM, BS, 0, stream>>>(agg16, Wf3, b3, nullptr, h3, N);

    // ---- pool + head ----
    k_pool_seg<<<NG, BS, 0, stream>>>(h3, batch, sums, cnt, N);
    k_head<<<1, 128, 0, stream>>>(sums, cnt, ge, Wl, bl, out, NG);
}

// Round 5
// 341.373 us; speedup vs baseline: 3.9418x; 1.1002x over previous
//
#include <hip/hip_runtime.h>
#include <hip/hip_bf16.h>
#include <math.h>

#define NG 128

typedef __attribute__((ext_vector_type(8))) short short8;
typedef __attribute__((ext_vector_type(4))) float float4v;

static __device__ __forceinline__ float bf2f(__hip_bfloat16 v) { return __bfloat162float(v); }

// ---------- CSR build ----------
__global__ void k_hist(const int* __restrict__ dst, int* __restrict__ counts, int e) {
    int i = blockIdx.x * blockDim.x + threadIdx.x;
    if (i < e) atomicAdd(&counts[dst[i]], 1);
}

__global__ void k_scan1(const int* __restrict__ counts, int* __restrict__ row_ptr,
                        int* __restrict__ blk_sums, int n) {
    __shared__ int s[256];
    int tid = threadIdx.x;
    int i = blockIdx.x * 256 + tid;
    int v = (i < n) ? counts[i] : 0;
    s[tid] = v;
    __syncthreads();
    for (int d = 1; d < 256; d <<= 1) {
        int t = (tid >= d) ? s[tid - d] : 0;
        __syncthreads();
        s[tid] += t;
        __syncthreads();
    }
    if (i < n) row_ptr[i] = s[tid] - v;  // exclusive
    if (tid == 255) blk_sums[blockIdx.x] = s[255];
}

__global__ void k_scan2(int* __restrict__ blk_sums, int nb) {
    __shared__ int s[512];
    int tid = threadIdx.x;
    int v = (tid < nb) ? blk_sums[tid] : 0;
    s[tid] = v;
    __syncthreads();
    for (int d = 1; d < 512; d <<= 1) {
        int t = (tid >= d) ? s[tid - d] : 0;
        __syncthreads();
        s[tid] += t;
        __syncthreads();
    }
    if (tid < nb) blk_sums[tid] = s[tid] - v;  // exclusive
}

__global__ void k_scan3(int* __restrict__ row_ptr, const int* __restrict__ blk_sums,
                        const int* __restrict__ counts, int* __restrict__ cursor,
                        float* __restrict__ dinv, int n, int e_total) {
    int i = blockIdx.x * 256 + threadIdx.x;
    if (i < n) {
        int v = row_ptr[i] + blk_sums[blockIdx.x];
        row_ptr[i] = v;
        cursor[i] = v;
        dinv[i] = rsqrtf((float)counts[i] + 1.0f);  // +1 self-loop
        if (i == n - 1) row_ptr[n] = e_total;
    }
}

// packed edge: .x = src index, .y = float weight bits
__global__ void k_scatter(const int* __restrict__ src, const int* __restrict__ dst,
                          const float* __restrict__ dinv, int* __restrict__ cursor,
                          int2* __restrict__ edges, int e) {
    int i = blockIdx.x * blockDim.x + threadIdx.x;
    if (i < e) {
        int s = src[i], d = dst[i];
        int pos = atomicAdd(&cursor[d], 1);
        edges[pos] = make_int2(s, __float_as_int(dinv[s] * dinv[d]));
    }
}

// ---------- layer-1 pull on raw 2-feature x (thread per node, 4x unroll) ----------
__global__ void k_pull2(const int* __restrict__ row_ptr, const int2* __restrict__ edges,
                        const float* __restrict__ x, const float* __restrict__ dinv,
                        float* __restrict__ out, int n) {
    int i = blockIdx.x * blockDim.x + threadIdx.x;
    if (i < n) {
        const float2* x2 = (const float2*)x;
        float dd = dinv[i], d2 = dd * dd;
        float2 xi = x2[i];
        float a0 = d2 * xi.x, a1 = d2 * xi.y;
        int lo = row_ptr[i], hi = row_ptr[i + 1];
        int k = lo;
        for (; k + 4 <= hi; k += 4) {
            int2 e0 = edges[k], e1 = edges[k + 1], e2 = edges[k + 2], e3 = edges[k + 3];
            float2 v0 = x2[e0.x], v1 = x2[e1.x], v2 = x2[e2.x], v3 = x2[e3.x];
            a0 += __int_as_float(e0.y) * v0.x; a1 += __int_as_float(e0.y) * v0.y;
            a0 += __int_as_float(e1.y) * v1.x; a1 += __int_as_float(e1.y) * v1.y;
            a0 += __int_as_float(e2.y) * v2.x; a1 += __int_as_float(e2.y) * v2.y;
            a0 += __int_as_float(e3.y) * v3.x; a1 += __int_as_float(e3.y) * v3.y;
        }
        for (; k < hi; k++) {
            int2 e = edges[k];
            float2 v = x2[e.x];
            a0 += __int_as_float(e.y) * v.x;
            a1 += __int_as_float(e.y) * v.y;
        }
        out[2 * i] = a0;
        out[2 * i + 1] = a1;
    }
}

// h1 = relu(aggx @ W1 + b1) -> bf16
__global__ void k_lin1(const float* __restrict__ aggx, const float* __restrict__ W1,
                       const float* __restrict__ b1, __hip_bfloat16* __restrict__ h, int n) {
    int t = blockIdx.x * blockDim.x + threadIdx.x;
    if (t < n * 64) {
        int i = t >> 6, j = t & 63;
        float v = aggx[2 * i] * W1[j] + aggx[2 * i + 1] * W1[64 + j] + b1[j];
        h[t] = __float2bfloat16(fmaxf(v, 0.0f));
    }
}

// ---------- width-64 pull aggregation (bf16 gather, fp32 acc, bf16 out) ----------
__global__ void k_agg(const int* __restrict__ row_ptr, const int2* __restrict__ edges,
                      const __hip_bfloat16* __restrict__ h, const float* __restrict__ dinv,
                      __hip_bfloat16* __restrict__ out, int n) {
    int node = blockIdx.x * (blockDim.x >> 6) + (threadIdx.x >> 6);
    int lane = threadIdx.x & 63;
    if (node >= n) return;
    float dd = dinv[node];
    float acc = dd * dd * bf2f(h[(size_t)node * 64 + lane]);
    int lo = row_ptr[node], hi = row_ptr[node + 1];
    for (int base = lo; base < hi; base += 64) {
        int take = hi - base; if (take > 64) take = 64;
        int take4 = (take + 3) & ~3;     // pad to 4; pad lanes carry w=0, s=0
        int sl = 0; float wl = 0.0f;
        if (base + lane < hi) {
            int2 e = edges[base + lane];
            sl = e.x; wl = __int_as_float(e.y);
        }
        for (int k = 0; k < take4; k += 4) {
            int   s0 = __shfl(sl, k),     s1 = __shfl(sl, k + 1);
            int   s2 = __shfl(sl, k + 2), s3 = __shfl(sl, k + 3);
            float w0 = __shfl(wl, k),     w1 = __shfl(wl, k + 1);
            float w2 = __shfl(wl, k + 2), w3 = __shfl(wl, k + 3);
            float v0 = bf2f(h[(size_t)s0 * 64 + lane]);
            float v1 = bf2f(h[(size_t)s1 * 64 + lane]);
            float v2 = bf2f(h[(size_t)s2 * 64 + lane]);
            float v3 = bf2f(h[(size_t)s3 * 64 + lane]);
            acc += w0 * v0; acc += w1 * v1; acc += w2 * v2; acc += w3 * v3;
        }
    }
    out[(size_t)node * 64 + lane] = __float2bfloat16(acc);
}

// ---------- pack W (64x64 fp32) into MFMA B-fragment order, bf16 ----------
__global__ void k_prepW(const float* __restrict__ W2, const float* __restrict__ W3,
                        __hip_bfloat16* __restrict__ Wf2, __hip_bfloat16* __restrict__ Wf3) {
    const float* W = blockIdx.x ? W3 : W2;
    __hip_bfloat16* Wf = blockIdx.x ? Wf3 : Wf2;
    int t = threadIdx.x;           // 0..511
    int c = t >> 6, l = t & 63;
    int jt = c >> 1, half = c & 1, nn = l & 15, q = l >> 4;
    #pragma unroll
    for (int j = 0; j < 8; j++) {
        int k = half * 32 + q * 8 + j;
        Wf[t * 8 + j] = __float2bfloat16(W[k * 64 + jt * 16 + nn]);
    }
}

// ---------- MFMA linear: out = act(in @ W + b); wave = 16 nodes ----------
template <int RELU>
__global__ void k_linM(const __hip_bfloat16* __restrict__ in,
                       const __hip_bfloat16* __restrict__ Wf,
                       const float* __restrict__ b,
                       __hip_bfloat16* __restrict__ out16, int n) {
    int wave = threadIdx.x >> 6, lane = threadIdx.x & 63;
    int nb = (blockIdx.x * (blockDim.x >> 6) + wave) * 16;
    if (nb >= n) return;
    int m = lane & 15, q = lane >> 4;
    int arow = nb + m; if (arow >= n) arow = n - 1;
    short8 a0 = *reinterpret_cast<const short8*>(in + (size_t)arow * 64 + q * 8);
    short8 a1 = *reinterpret_cast<const short8*>(in + (size_t)arow * 64 + 32 + q * 8);
    #pragma unroll
    for (int jt = 0; jt < 4; jt++) {
        short8 bf0 = *reinterpret_cast<const short8*>(Wf + ((size_t)(jt * 2 + 0) * 64 + lane) * 8);
        short8 bf1 = *reinterpret_cast<const short8*>(Wf + ((size_t)(jt * 2 + 1) * 64 + lane) * 8);
        float4v d = {0.0f, 0.0f, 0.0f, 0.0f};
        d = __builtin_amdgcn_mfma_f32_16x16x32_bf16(a0, bf0, d, 0, 0, 0);
        d = __builtin_amdgcn_mfma_f32_16x16x32_bf16(a1, bf1, d, 0, 0, 0);
        float bias = b[jt * 16 + m];           // C/D col = lane&15
        #pragma unroll
        for (int r = 0; r < 4; r++) {
            int row = q * 4 + r;               // C/D row = quad*4 + reg
            int node = nb + row;
            if (node < n) {
                float v = d[r] + bias;
                if (RELU) v = fmaxf(v, 0.0f);
                out16[(size_t)node * 64 + jt * 16 + m] = __float2bfloat16(v);
            }
        }
    }
}

// ---------- node-parallel pool: chunk of 128 nodes per block ----------
// thread = (r, j): r-th node lane (stride 4), feature j; flush on graph change
__global__ void k_pool_par(const __hip_bfloat16* __restrict__ h,
                           const int* __restrict__ batch,
                           float* __restrict__ sums, int n) {
    int base = blockIdx.x * 128;
    int lim = base + 128; if (lim > n) lim = n;
    int j = threadIdx.x & 63, r = threadIdx.x >> 6;
    float acc = 0.0f; int gcur = -1;
    for (int i = base + r; i < lim; i += 4) {
        int g = batch[i];
        if (g != gcur) {
            if (gcur >= 0) atomicAdd(&sums[gcur * 64 + j], acc);
            acc = 0.0f; gcur = g;
        }
        acc += bf2f(h[(size_t)i * 64 + j]);
    }
    if (gcur >= 0) atomicAdd(&sums[gcur * 64 + j], acc);
}

// ---------- head (computes counts via binary search on sorted batch) ----------
__device__ inline int lower_bound_i(const int* __restrict__ a, int n, int key) {
    int lo = 0, hi = n;
    while (lo < hi) {
        int mid = (lo + hi) >> 1;
        if (a[mid] < key) lo = mid + 1; else hi = mid;
    }
    return lo;
}

__global__ void k_head(const float* __restrict__ sums, const int* __restrict__ batch,
                       const float* __restrict__ ge, const float* __restrict__ Wl,
                       const float* __restrict__ bl, float* __restrict__ out,
                       int n, int ng) {
    int g = blockIdx.x * blockDim.x + threadIdx.x;
    if (g < ng) {
        int lo = lower_bound_i(batch, n, g);
        int hi = lower_bound_i(batch, n, g + 1);
        float c = fmaxf((float)(hi - lo), 1.0f);
        float z[5];
        for (int cl = 0; cl < 5; cl++) z[cl] = bl[cl];
        for (int k = 0; k < 64; k++) {
            float p = sums[g * 64 + k] / c;
            for (int cl = 0; cl < 5; cl++) z[cl] += p * Wl[k * 5 + cl];
        }
        for (int k = 0; k < 64; k++) {
            float p = ge[g * 64 + k];
            for (int cl = 0; cl < 5; cl++) z[cl] += p * Wl[(64 + k) * 5 + cl];
        }
        float m = z[0];
        for (int cl = 1; cl < 5; cl++) m = fmaxf(m, z[cl]);
        float s = 0.0f;
        for (int cl = 0; cl < 5; cl++) s += expf(z[cl] - m);
        float lse = m + logf(s);
        for (int cl = 0; cl < 5; cl++) out[g * 5 + cl] = z[cl] - lse;
    }
}

extern "C" void kernel_launch(void* const* d_in, const int* in_sizes, int n_in,
                              void* d_out, int out_size, void* d_ws, size_t ws_size,
                              hipStream_t stream) {
    const float* x    = (const float*)d_in[0];
    const int*   ei   = (const int*)d_in[1];
    const int*   batch= (const int*)d_in[2];
    const float* ge   = (const float*)d_in[3];
    const float* W1   = (const float*)d_in[4];
    const float* b1   = (const float*)d_in[5];
    const float* W2   = (const float*)d_in[6];
    const float* b2   = (const float*)d_in[7];
    const float* W3   = (const float*)d_in[8];
    const float* b3   = (const float*)d_in[9];
    const float* Wl   = (const float*)d_in[10];
    const float* bl   = (const float*)d_in[11];
    float* out = (float*)d_out;

    const int N = in_sizes[0] / 2;   // x is [N,2]
    const int E = in_sizes[1] / 2;   // edge_index is [2,E]
    const int* src = ei;
    const int* dst = ei + E;

    // ---- workspace layout (segments 16B-aligned) ----
    char* wsb = (char*)d_ws;
    float* dinv   = (float*)wsb;                wsb += (size_t)N * 4;
    float* aggx   = (float*)wsb;                wsb += (size_t)2 * N * 4;
    __hip_bfloat16* h16  = (__hip_bfloat16*)wsb; wsb += (size_t)64 * N * 2;  // h1 -> h2 -> h3
    __hip_bfloat16* agg16= (__hip_bfloat16*)wsb; wsb += (size_t)64 * N * 2;
    float* sums   = (float*)wsb;                wsb += (size_t)NG * 64 * 4;
    __hip_bfloat16* Wf2 = (__hip_bfloat16*)wsb; wsb += 4096 * 2;
    __hip_bfloat16* Wf3 = (__hip_bfloat16*)wsb; wsb += 4096 * 2;
    int2*  edges  = (int2*)wsb;                 wsb += (size_t)E * 8;
    int*   counts = (int*)wsb;                  wsb += (size_t)N * 4;
    int*   cursor = (int*)wsb;                  wsb += (size_t)N * 4;
    int*   row_ptr= (int*)wsb;                  wsb += (size_t)(N + 1) * 4;
    int*   blk_sums=(int*)wsb;                  wsb += 512 * 4;

    const int BS = 256;
    int gN   = (N + BS - 1) / BS;
    int gE   = (E + BS - 1) / BS;
    int gN64 = (N * 64 + BS - 1) / BS;
    int gW   = (N + 3) / 4;                      // k_agg: 4 waves per block
    int gM   = ((N + 15) / 16 + 3) / 4;          // k_linM: 4 waves * 16 nodes
    int gP   = (N + 127) / 128;                  // pool chunks

    // ---- CSR build ----
    hipMemsetAsync(counts, 0, (size_t)N * 4, stream);
    hipMemsetAsync(sums, 0, (size_t)NG * 64 * 4, stream);
    k_hist<<<gE, BS, 0, stream>>>(dst, counts, E);
    k_scan1<<<gN, BS, 0, stream>>>(counts, row_ptr, blk_sums, N);
    k_scan2<<<1, 512, 0, stream>>>(blk_sums, gN);
    k_scan3<<<gN, BS, 0, stream>>>(row_ptr, blk_sums, counts, cursor, dinv, N, E);
    k_scatter<<<gE, BS, 0, stream>>>(src, dst, dinv, cursor, edges, E);
    k_prepW<<<2, 512, 0, stream>>>(W2, W3, Wf2, Wf3);

    // ---- layer 1 ----
    k_pull2<<<gN, BS, 0, stream>>>(row_ptr, edges, x, dinv, aggx, N);
    k_lin1<<<gN64, BS, 0, stream>>>(aggx, W1, b1, h16, N);

    // ---- layer 2: agg = A@h1 ; h2 = relu(agg@W2+b2) (overwrites h1) ----
    k_agg<<<gW, BS, 0, stream>>>(row_ptr, edges, h16, dinv, agg16, N);
    k_linM<1><<<gM, BS, 0, stream>>>(agg16, Wf2, b2, h16, N);

    // ---- layer 3: agg = A@h2 ; h3 = agg@W3+b3 -> bf16 (overwrites h2) ----
    k_agg<<<gW, BS, 0, stream>>>(row_ptr, edges, h16, dinv, agg16, N);
    k_linM<0><<<gM, BS, 0, stream>>>(agg16, Wf3, b3, h16, N);

    // ---- pool + head ----
    k_pool_par<<<gP, BS, 0, stream>>>(h16, batch, sums, N);
    k_head<<<1, 128, 0, stream>>>(sums, batch, ge, Wl, bl, out, N, NG);
}